// Round 2
// baseline (483.492 us; speedup 1.0000x reference)
//
#include <hip/hip_runtime.h>
#include <hip/hip_bf16.h>

#define NN 8192
#define INC 128
#define OUTC 64

typedef __attribute__((ext_vector_type(8))) short bf16x8;
typedef __attribute__((ext_vector_type(4))) float f32x4;
typedef __attribute__((ext_vector_type(4))) int i32x4;

static __device__ __forceinline__ unsigned short f2bf(float x) {
    unsigned int u = __builtin_bit_cast(unsigned int, x);
    u += 0x7fffu + ((u >> 16) & 1u);   // RNE, finite only
    return (unsigned short)(u >> 16);
}
static __device__ __forceinline__ float bf2f(unsigned short b) {
    unsigned int u = ((unsigned int)b) << 16;
    return __builtin_bit_cast(float, u);
}

// ---------------------------------------------------------------------------
// KA: bitpack adj (256 MB int32) -> 8 MB bitmask, natural bit order.
// Wave-iter = 256 ints: lane reads i32x4 at base+4*lane -> 4-bit nibble,
// OR-reduce nibbles within each 16-lane group -> 4x u64 (64 cols each).
// Pure streaming: coalesced 4 KB loads/iter, 32 B store/iter.
// ---------------------------------------------------------------------------
__global__ __launch_bounds__(256) void ka_pack(const int* __restrict__ adj,
                                               unsigned long long* __restrict__ msk)
{
    const int lane = threadIdx.x & 63;
    const int wid  = (blockIdx.x * 256 + threadIdx.x) >> 6;   // 8192 waves
    const int l16  = lane & 15;
    const int g16  = lane >> 4;
    // 262144 wave-iters total, 32 consecutive per wave
#pragma unroll 4
    for (int i = 0; i < 32; ++i) {
        const size_t base = ((size_t)wid * 32 + i) * 256;
        i32x4 v = *(const i32x4*)(adj + base + 4 * lane);
        unsigned int nib = (v[0] > 0 ? 1u : 0u) | (v[1] > 0 ? 2u : 0u)
                         | (v[2] > 0 ? 4u : 0u) | (v[3] > 0 ? 8u : 0u);
        unsigned long long m = (unsigned long long)nib << (4 * l16);
        m |= __shfl_xor(m, 1, 64);
        m |= __shfl_xor(m, 2, 64);
        m |= __shfl_xor(m, 4, 64);
        m |= __shfl_xor(m, 8, 64);
        if (l16 == 0) msk[base / 64 + g16] = m;
    }
}

// ---------------------------------------------------------------------------
// K1: Wh = h @ W (bf16, TRANSPOSED whbt[ch][row]), f = Wh@a1, g = Wh@a2.
// Wave = one row; LDS transpose so whbt stores are ushort4 (coalesced-ish).
// ---------------------------------------------------------------------------
__global__ __launch_bounds__(256) void k1_wh(const float* __restrict__ h,
                                             const float* __restrict__ W,
                                             const float* __restrict__ a,
                                             unsigned short* __restrict__ whbt,
                                             float* __restrict__ f,
                                             float* __restrict__ g)
{
    const int wave = threadIdx.x >> 6;
    const int ch   = threadIdx.x & 63;
    const int row  = blockIdx.x * 4 + wave;
    const f32x4* h4 = (const f32x4*)(h + (size_t)row * INC);
    float acc = 0.f;
#pragma unroll 8
    for (int k4 = 0; k4 < INC / 4; ++k4) {
        f32x4 hv = h4[k4];
        acc += hv[0] * W[(k4 * 4 + 0) * OUTC + ch];
        acc += hv[1] * W[(k4 * 4 + 1) * OUTC + ch];
        acc += hv[2] * W[(k4 * 4 + 2) * OUTC + ch];
        acc += hv[3] * W[(k4 * 4 + 3) * OUTC + ch];
    }
    __shared__ unsigned short tr[64][4];
    tr[ch][wave] = f2bf(acc);

    float v1 = acc * a[ch];
    float v2 = acc * a[64 + ch];
#pragma unroll
    for (int m = 1; m < 64; m <<= 1) {
        v1 += __shfl_xor(v1, m, 64);
        v2 += __shfl_xor(v2, m, 64);
    }
    if (ch == 0) { f[row] = v1; g[row] = v2; }
    __syncthreads();
    if (wave == 0) {
        ushort4 o = *(const ushort4*)&tr[ch][0];
        *(ushort4*)(whbt + (size_t)ch * NN + blockIdx.x * 4) = o;
    }
}

// ---------------------------------------------------------------------------
// K2: global max of g (analytic softmax bound)
// ---------------------------------------------------------------------------
__global__ __launch_bounds__(256) void k2_gmax(const float* __restrict__ g,
                                               float* __restrict__ gmax)
{
    __shared__ float red[256];
    float m = -1e30f;
    for (int i = threadIdx.x; i < NN; i += 256) m = fmaxf(m, g[i]);
    red[threadIdx.x] = m;
    __syncthreads();
    for (int s = 128; s > 0; s >>= 1) {
        if ((int)threadIdx.x < s) red[threadIdx.x] = fmaxf(red[threadIdx.x], red[threadIdx.x + s]);
        __syncthreads();
    }
    if (threadIdx.x == 0) *gmax = red[0];
}

// ---------------------------------------------------------------------------
// K3: flash-style masked-softmax-weighted accumulation off the BITMASK.
// Block = 4 waves; wave = 16 rows; 32 cols/step. blockIdx.y = j-chunk.
// Per lane per step: 1 u32 mask + 8 g + 4 B-fragments (all cache-resident).
// ---------------------------------------------------------------------------
__global__ __launch_bounds__(256) void k3_attn(const unsigned int* __restrict__ msk,
                                               const unsigned short* __restrict__ whbt,
                                               const float* __restrict__ f,
                                               const float* __restrict__ g,
                                               const float* __restrict__ gmaxp,
                                               float* __restrict__ accP,
                                               float* __restrict__ lP,
                                               int colsPerChunk)
{
    const int lane = threadIdx.x & 63;
    const int wave = threadIdx.x >> 6;
    const int lr16 = lane & 15;
    const int kg   = lane >> 4;
    const int rowBase = blockIdx.x * 64 + wave * 16;
    const int r = rowBase + lr16;
    const int chunk = blockIdx.y;
    const int jStart = chunk * colsPerChunk;

    const float L2E = 1.4426950408889634f;
    const float fr = f[r];
    const float gmax = *gmaxp;
    float mm = fr + gmax;
    mm = fmaxf(mm, 0.5f * mm);          // LeakyReLU(f_r + gmax) >= all row scores
    const float mL = mm * L2E;

    f32x4 acc0 = {0.f, 0.f, 0.f, 0.f};
    f32x4 acc1 = {0.f, 0.f, 0.f, 0.f};
    f32x4 acc2 = {0.f, 0.f, 0.f, 0.f};
    f32x4 acc3 = {0.f, 0.f, 0.f, 0.f};
    float ls = 0.f;

    const unsigned int* mrow = msk + (size_t)r * (NN / 32);
    const unsigned short* wb0 = whbt + (size_t)(0 * 16 + lr16) * NN;
    const unsigned short* wb1 = whbt + (size_t)(1 * 16 + lr16) * NN;
    const unsigned short* wb2 = whbt + (size_t)(2 * 16 + lr16) * NN;
    const unsigned short* wb3 = whbt + (size_t)(3 * 16 + lr16) * NN;

#pragma unroll 2
    for (int j0 = jStart; j0 < jStart + colsPerChunk; j0 += 32) {
        const int jl = j0 + kg * 8;
        unsigned int mw = mrow[j0 >> 5];
        unsigned int myb = (mw >> (kg * 8)) & 0xffu;
        f32x4 g0  = *(const f32x4*)(g + jl);
        f32x4 g1  = *(const f32x4*)(g + jl + 4);
        bf16x8 b0 = *(const bf16x8*)(wb0 + jl);
        bf16x8 b1 = *(const bf16x8*)(wb1 + jl);
        bf16x8 b2 = *(const bf16x8*)(wb2 + jl);
        bf16x8 b3 = *(const bf16x8*)(wb3 + jl);

        bf16x8 af;
#pragma unroll
        for (int t = 0; t < 8; ++t) {
            float gj = (t < 4) ? g0[t] : g1[t - 4];
            float s  = fr + gj;
            float lr = fmaxf(s, 0.5f * s);                     // LeakyReLU, alpha=0.5
            float w  = __builtin_amdgcn_exp2f(lr * L2E - mL);  // <= 1
            w = (myb & (1u << t)) ? w : 0.f;
            unsigned short b = f2bf(w);
            af[t] = (short)b;
            ls += bf2f(b);      // row-sum from the SAME bf16-rounded weights
        }
        acc0 = __builtin_amdgcn_mfma_f32_16x16x32_bf16(af, b0, acc0, 0, 0, 0);
        acc1 = __builtin_amdgcn_mfma_f32_16x16x32_bf16(af, b1, acc1, 0, 0, 0);
        acc2 = __builtin_amdgcn_mfma_f32_16x16x32_bf16(af, b2, acc2, 0, 0, 0);
        acc3 = __builtin_amdgcn_mfma_f32_16x16x32_bf16(af, b3, acc3, 0, 0, 0);
    }

    ls += __shfl_xor(ls, 16, 64);
    ls += __shfl_xor(ls, 32, 64);
    if (lane < 16) lP[(size_t)chunk * NN + rowBase + lane] = ls;

    float* ap = accP + (size_t)chunk * NN * OUTC;
#pragma unroll
    for (int q = 0; q < 4; ++q) {
        const int rm = rowBase + kg * 4 + q;
        ap[(size_t)rm * OUTC +  0 + lr16] = acc0[q];
        ap[(size_t)rm * OUTC + 16 + lr16] = acc1[q];
        ap[(size_t)rm * OUTC + 32 + lr16] = acc2[q];
        ap[(size_t)rm * OUTC + 48 + lr16] = acc3[q];
    }
}

// ---------------------------------------------------------------------------
// K4: combine j-chunk partials, normalize, final LeakyReLU
// ---------------------------------------------------------------------------
__global__ __launch_bounds__(256) void k4_final(const float* __restrict__ accP,
                                                const float* __restrict__ lP,
                                                float* __restrict__ out, int js)
{
    const int gid = blockIdx.x * 256 + threadIdx.x;
    const int row = gid >> 6;
    const int ch  = gid & 63;
    float av = 0.f, lv = 0.f;
    for (int c = 0; c < js; ++c) {
        av += accP[((size_t)c * NN + row) * OUTC + ch];
        lv += lP[(size_t)c * NN + row];
    }
    if (lv == 0.f) lv = 1.f;            // unreachable for this data; NaN guard
    const float hv = av / lv;
    out[(size_t)row * OUTC + ch] = fmaxf(hv, 0.5f * hv);
}

extern "C" void kernel_launch(void* const* d_in, const int* in_sizes, int n_in,
                              void* d_out, int out_size, void* d_ws, size_t ws_size,
                              hipStream_t stream)
{
    const float* h   = (const float*)d_in[0];
    const int*   adj = (const int*)d_in[1];
    const float* W   = (const float*)d_in[2];
    const float* a   = (const float*)d_in[3];
    float* out = (float*)d_out;

    char* ws = (char*)d_ws;
    unsigned short* whbt = (unsigned short*)ws;
    size_t off = (size_t)OUTC * NN * sizeof(unsigned short);   // 1 MB
    float* f = (float*)(ws + off); off += (size_t)NN * 4;
    float* g = (float*)(ws + off); off += (size_t)NN * 4;
    float* gmax = (float*)(ws + off); off += 256;
    unsigned long long* msk = (unsigned long long*)(ws + off);
    off += (size_t)NN * NN / 8;                                // 8 MB bitmask

    const size_t perChunk = (size_t)NN * OUTC * 4 + (size_t)NN * 4;
    int js = 16;
    while (js > 1 && off + (size_t)js * perChunk > ws_size) js >>= 1;
    float* accP = (float*)(ws + off); off += (size_t)js * NN * OUTC * 4;
    float* lP   = (float*)(ws + off);

    ka_pack<<<dim3(2048), 256, 0, stream>>>(adj, msk);
    k1_wh<<<dim3(NN / 4), 256, 0, stream>>>(h, W, a, whbt, f, g);
    k2_gmax<<<1, 256, 0, stream>>>(g, gmax);
    const int colsPerChunk = NN / js;
    k3_attn<<<dim3(NN / 64, js), 256, 0, stream>>>((const unsigned int*)msk, whbt,
                                                   f, g, gmax, accP, lP, colsPerChunk);
    k4_final<<<dim3(NN * OUTC / 256), 256, 0, stream>>>(accP, lP, out, js);
}

// Round 3
// 441.500 us; speedup vs baseline: 1.0951x; 1.0951x over previous
//
#include <hip/hip_runtime.h>
#include <hip/hip_bf16.h>

#define NN 8192
#define INC 128
#define OUTC 64

typedef __attribute__((ext_vector_type(8))) short bf16x8;
typedef __attribute__((ext_vector_type(4))) float f32x4;
typedef __attribute__((ext_vector_type(4))) int i32x4;

static __device__ __forceinline__ unsigned short f2bf(float x) {
    unsigned int u = __builtin_bit_cast(unsigned int, x);
    u += 0x7fffu + ((u >> 16) & 1u);   // RNE, finite only
    return (unsigned short)(u >> 16);
}

// ---------------------------------------------------------------------------
// KA: bitpack adj (256 MB int32) -> 8 MB bitmask, natural bit order.
// ---------------------------------------------------------------------------
__global__ __launch_bounds__(256) void ka_pack(const int* __restrict__ adj,
                                               unsigned long long* __restrict__ msk)
{
    const int lane = threadIdx.x & 63;
    const int wid  = (blockIdx.x * 256 + threadIdx.x) >> 6;   // 8192 waves
    const int l16  = lane & 15;
    const int g16  = lane >> 4;
#pragma unroll 4
    for (int i = 0; i < 32; ++i) {
        const size_t base = ((size_t)wid * 32 + i) * 256;
        i32x4 v = *(const i32x4*)(adj + base + 4 * lane);
        unsigned int nib = (v[0] > 0 ? 1u : 0u) | (v[1] > 0 ? 2u : 0u)
                         | (v[2] > 0 ? 4u : 0u) | (v[3] > 0 ? 8u : 0u);
        unsigned long long m = (unsigned long long)nib << (4 * l16);
        m |= __shfl_xor(m, 1, 64);
        m |= __shfl_xor(m, 2, 64);
        m |= __shfl_xor(m, 4, 64);
        m |= __shfl_xor(m, 8, 64);
        if (l16 == 0) msk[base / 64 + g16] = m;
    }
}

// ---------------------------------------------------------------------------
// K1: Wh = h @ W, written directly in FRAGMENT-MAJOR bf16 layout:
//   whF[(seg*64 + chan)*8 .. +8] = Wh[seg*8 .. seg*8+8][chan]   (16 B frag)
// Block = 512 thr = 8 waves = 8 rows = one seg. Also f = Wh@a1, g = Wh@a2.
// ---------------------------------------------------------------------------
__global__ __launch_bounds__(512) void k1_wh(const float* __restrict__ h,
                                             const float* __restrict__ W,
                                             const float* __restrict__ a,
                                             unsigned short* __restrict__ whF,
                                             float* __restrict__ f,
                                             float* __restrict__ g)
{
    const int wave = threadIdx.x >> 6;
    const int ch   = threadIdx.x & 63;
    const int seg  = blockIdx.x;
    const int row  = seg * 8 + wave;
    const f32x4* h4 = (const f32x4*)(h + (size_t)row * INC);
    float acc = 0.f;
#pragma unroll 8
    for (int k4 = 0; k4 < INC / 4; ++k4) {
        f32x4 hv = h4[k4];
        acc += hv[0] * W[(k4 * 4 + 0) * OUTC + ch];
        acc += hv[1] * W[(k4 * 4 + 1) * OUTC + ch];
        acc += hv[2] * W[(k4 * 4 + 2) * OUTC + ch];
        acc += hv[3] * W[(k4 * 4 + 3) * OUTC + ch];
    }
    __shared__ unsigned short tr[64][8];
    tr[ch][wave] = f2bf(acc);

    float v1 = acc * a[ch];
    float v2 = acc * a[64 + ch];
#pragma unroll
    for (int m = 1; m < 64; m <<= 1) {
        v1 += __shfl_xor(v1, m, 64);
        v2 += __shfl_xor(v2, m, 64);
    }
    if (ch == 0) { f[row] = v1; g[row] = v2; }
    __syncthreads();
    if (threadIdx.x < 64) {
        bf16x8 frag = *(const bf16x8*)&tr[threadIdx.x][0];
        *(bf16x8*)(whF + ((size_t)seg * 64 + threadIdx.x) * 8) = frag;  // coalesced 1 KB
    }
}

// ---------------------------------------------------------------------------
// K2: global max of g (analytic softmax bound)
// ---------------------------------------------------------------------------
__global__ __launch_bounds__(256) void k2_gmax(const float* __restrict__ g,
                                               float* __restrict__ gmax)
{
    __shared__ float red[256];
    float m = -1e30f;
    for (int i = threadIdx.x; i < NN; i += 256) m = fmaxf(m, g[i]);
    red[threadIdx.x] = m;
    __syncthreads();
    for (int s = 128; s > 0; s >>= 1) {
        if ((int)threadIdx.x < s) red[threadIdx.x] = fmaxf(red[threadIdx.x], red[threadIdx.x + s]);
        __syncthreads();
    }
    if (threadIdx.x == 0) *gmax = red[0];
}

// ---------------------------------------------------------------------------
// K3: masked-softmax-weighted accumulation off the bitmask + fragment-major Wh.
// Block = 4 waves; wave = 16 rows; 32 cols/step; blockIdx.y = j-chunk.
// Row-sum computed by a 5th MFMA against an all-ones B-fragment (same
// bf16-rounded weights -> numerics identical to explicit summation).
// ---------------------------------------------------------------------------
__global__ __launch_bounds__(256) void k3_attn(const unsigned int* __restrict__ msk,
                                               const unsigned short* __restrict__ whF,
                                               const float* __restrict__ f,
                                               const float* __restrict__ g,
                                               const float* __restrict__ gmaxp,
                                               float* __restrict__ accP,
                                               float* __restrict__ lP,
                                               int colsPerChunk)
{
    const int lane = threadIdx.x & 63;
    const int wave = threadIdx.x >> 6;
    const int lr16 = lane & 15;
    const int kg   = lane >> 4;
    const int rowBase = blockIdx.x * 64 + wave * 16;
    const int r = rowBase + lr16;
    const int chunk = blockIdx.y;
    const int jStart = chunk * colsPerChunk;

    const float L2E = 1.4426950408889634f;
    const float fr = f[r];
    const float gmax = *gmaxp;
    float mm = fr + gmax;
    mm = fmaxf(mm, 0.5f * mm);          // LeakyReLU(f_r + gmax) >= all row scores
    const float mL  = mm * L2E;
    const float frE = fr * L2E - mL;    // se' = g*L2E + frE
    const float hm  = -0.5f * mL;       // u = 0.5*se' + hm

    f32x4 acc0 = {0.f, 0.f, 0.f, 0.f};
    f32x4 acc1 = {0.f, 0.f, 0.f, 0.f};
    f32x4 acc2 = {0.f, 0.f, 0.f, 0.f};
    f32x4 acc3 = {0.f, 0.f, 0.f, 0.f};
    f32x4 accl = {0.f, 0.f, 0.f, 0.f};
    bf16x8 ones;
#pragma unroll
    for (int t = 0; t < 8; ++t) ones[t] = (short)0x3F80;      // bf16 1.0

    const unsigned int* mrow = msk + (size_t)r * (NN / 32);

#pragma unroll 2
    for (int j0 = jStart; j0 < jStart + colsPerChunk; j0 += 32) {
        const int jl = j0 + kg * 8;
        unsigned int mw = mrow[j0 >> 5];
        unsigned int myb = (mw >> (kg * 8)) & 0xffu;
        f32x4 g0  = *(const f32x4*)(g + jl);
        f32x4 g1  = *(const f32x4*)(g + jl + 4);
        // fragment-major: frag(seg, chan) at whF + (seg*64 + chan)*8
        const size_t segB = (size_t)((j0 >> 3) + kg) * 64;
        bf16x8 b0 = *(const bf16x8*)(whF + (segB +  0 + lr16) * 8);
        bf16x8 b1 = *(const bf16x8*)(whF + (segB + 16 + lr16) * 8);
        bf16x8 b2 = *(const bf16x8*)(whF + (segB + 32 + lr16) * 8);
        bf16x8 b3 = *(const bf16x8*)(whF + (segB + 48 + lr16) * 8);

        bf16x8 af;
#pragma unroll
        for (int t = 0; t < 8; ++t) {
            float gj = (t < 4) ? g0[t] : g1[t - 4];
            float se = __builtin_fmaf(gj, L2E, frE);           // s*L2E - mL
            float u  = __builtin_fmaf(0.5f, se, hm);           // 0.5*s*L2E - mL
            float w  = __builtin_amdgcn_exp2f(fmaxf(se, u));   // exp2(LR(s)*L2E - mL) <= 1
            w = (myb & (1u << t)) ? w : 0.f;
            af[t] = (short)f2bf(w);
        }
        acc0 = __builtin_amdgcn_mfma_f32_16x16x32_bf16(af, b0, acc0, 0, 0, 0);
        acc1 = __builtin_amdgcn_mfma_f32_16x16x32_bf16(af, b1, acc1, 0, 0, 0);
        acc2 = __builtin_amdgcn_mfma_f32_16x16x32_bf16(af, b2, acc2, 0, 0, 0);
        acc3 = __builtin_amdgcn_mfma_f32_16x16x32_bf16(af, b3, acc3, 0, 0, 0);
        accl = __builtin_amdgcn_mfma_f32_16x16x32_bf16(af, ones, accl, 0, 0, 0);
    }

    // accl D-layout: col = lr16 (all cols equal), row-in-tile = kg*4 + q
    if (lr16 == 0) {
#pragma unroll
        for (int q = 0; q < 4; ++q)
            lP[(size_t)chunk * NN + rowBase + kg * 4 + q] = accl[q];
    }

    float* ap = accP + (size_t)chunk * NN * OUTC;
#pragma unroll
    for (int q = 0; q < 4; ++q) {
        const int rm = rowBase + kg * 4 + q;
        ap[(size_t)rm * OUTC +  0 + lr16] = acc0[q];
        ap[(size_t)rm * OUTC + 16 + lr16] = acc1[q];
        ap[(size_t)rm * OUTC + 32 + lr16] = acc2[q];
        ap[(size_t)rm * OUTC + 48 + lr16] = acc3[q];
    }
}

// ---------------------------------------------------------------------------
// K4: combine j-chunk partials, normalize, final LeakyReLU
// ---------------------------------------------------------------------------
__global__ __launch_bounds__(256) void k4_final(const float* __restrict__ accP,
                                                const float* __restrict__ lP,
                                                float* __restrict__ out, int js)
{
    const int gid = blockIdx.x * 256 + threadIdx.x;
    const int row = gid >> 6;
    const int ch  = gid & 63;
    float av = 0.f, lv = 0.f;
    for (int c = 0; c < js; ++c) {
        av += accP[((size_t)c * NN + row) * OUTC + ch];
        lv += lP[(size_t)c * NN + row];
    }
    if (lv == 0.f) lv = 1.f;            // NaN guard (unreachable for this data)
    const float hv = av / lv;
    out[(size_t)row * OUTC + ch] = fmaxf(hv, 0.5f * hv);
}

extern "C" void kernel_launch(void* const* d_in, const int* in_sizes, int n_in,
                              void* d_out, int out_size, void* d_ws, size_t ws_size,
                              hipStream_t stream)
{
    const float* h   = (const float*)d_in[0];
    const int*   adj = (const int*)d_in[1];
    const float* W   = (const float*)d_in[2];
    const float* a   = (const float*)d_in[3];
    float* out = (float*)d_out;

    char* ws = (char*)d_ws;
    unsigned short* whF = (unsigned short*)ws;
    size_t off = (size_t)OUTC * NN * sizeof(unsigned short);   // 1 MB fragment-major Wh
    float* f = (float*)(ws + off); off += (size_t)NN * 4;
    float* g = (float*)(ws + off); off += (size_t)NN * 4;
    float* gmax = (float*)(ws + off); off += 256;
    unsigned long long* msk = (unsigned long long*)(ws + off);
    off += (size_t)NN * NN / 8;                                // 8 MB bitmask

    const size_t perChunk = (size_t)NN * OUTC * 4 + (size_t)NN * 4;
    int js = 16;
    while (js > 1 && off + (size_t)js * perChunk > ws_size) js >>= 1;
    float* accP = (float*)(ws + off); off += (size_t)js * NN * OUTC * 4;
    float* lP   = (float*)(ws + off);

    ka_pack<<<dim3(2048), 256, 0, stream>>>(adj, msk);
    k1_wh<<<dim3(NN / 8), 512, 0, stream>>>(h, W, a, whF, f, g);
    k2_gmax<<<1, 256, 0, stream>>>(g, gmax);
    const int colsPerChunk = NN / js;
    k3_attn<<<dim3(NN / 64, js), 256, 0, stream>>>((const unsigned int*)msk, whF,
                                                   f, g, gmax, accP, lP, colsPerChunk);
    k4_final<<<dim3(NN * OUTC / 256), 256, 0, stream>>>(accP, lP, out, js);
}

// Round 12
// 430.023 us; speedup vs baseline: 1.1243x; 1.0267x over previous
//
#include <hip/hip_runtime.h>
#include <hip/hip_bf16.h>

#define NN 8192
#define INC 128
#define OUTC 64

typedef __attribute__((ext_vector_type(8))) short bf16x8;
typedef __attribute__((ext_vector_type(4))) float f32x4;
typedef __attribute__((ext_vector_type(4))) int i32x4;

static __device__ __forceinline__ unsigned short f2bf(float x) {
    unsigned int u = __builtin_bit_cast(unsigned int, x);
    u += 0x7fffu + ((u >> 16) & 1u);   // RNE, finite only
    return (unsigned short)(u >> 16);
}

// ---------------------------------------------------------------------------
// KA: bitpack adj (256 MB int32) -> 8 MB bitmask, natural bit order.
// ---------------------------------------------------------------------------
__global__ __launch_bounds__(256) void ka_pack(const int* __restrict__ adj,
                                               unsigned long long* __restrict__ msk)
{
    const int lane = threadIdx.x & 63;
    const int wid  = (blockIdx.x * 256 + threadIdx.x) >> 6;   // 8192 waves
    const int l16  = lane & 15;
    const int g16  = lane >> 4;
#pragma unroll 4
    for (int i = 0; i < 32; ++i) {
        const size_t base = ((size_t)wid * 32 + i) * 256;
        i32x4 v = *(const i32x4*)(adj + base + 4 * lane);
        unsigned int nib = (v[0] > 0 ? 1u : 0u) | (v[1] > 0 ? 2u : 0u)
                         | (v[2] > 0 ? 4u : 0u) | (v[3] > 0 ? 8u : 0u);
        unsigned long long m = (unsigned long long)nib << (4 * l16);
        m |= __shfl_xor(m, 1, 64);
        m |= __shfl_xor(m, 2, 64);
        m |= __shfl_xor(m, 4, 64);
        m |= __shfl_xor(m, 8, 64);
        if (l16 == 0) msk[base / 64 + g16] = m;
    }
}

// ---------------------------------------------------------------------------
// K1: Wh = h @ W in fragment-major bf16 layout; f = Wh@a1, g = Wh@a2.
// ---------------------------------------------------------------------------
__global__ __launch_bounds__(512) void k1_wh(const float* __restrict__ h,
                                             const float* __restrict__ W,
                                             const float* __restrict__ a,
                                             unsigned short* __restrict__ whF,
                                             float* __restrict__ f,
                                             float* __restrict__ g)
{
    const int wave = threadIdx.x >> 6;
    const int ch   = threadIdx.x & 63;
    const int seg  = blockIdx.x;
    const int row  = seg * 8 + wave;
    const f32x4* h4 = (const f32x4*)(h + (size_t)row * INC);
    float acc = 0.f;
#pragma unroll 8
    for (int k4 = 0; k4 < INC / 4; ++k4) {
        f32x4 hv = h4[k4];
        acc += hv[0] * W[(k4 * 4 + 0) * OUTC + ch];
        acc += hv[1] * W[(k4 * 4 + 1) * OUTC + ch];
        acc += hv[2] * W[(k4 * 4 + 2) * OUTC + ch];
        acc += hv[3] * W[(k4 * 4 + 3) * OUTC + ch];
    }
    __shared__ unsigned short tr[64][8];
    tr[ch][wave] = f2bf(acc);

    float v1 = acc * a[ch];
    float v2 = acc * a[64 + ch];
#pragma unroll
    for (int m = 1; m < 64; m <<= 1) {
        v1 += __shfl_xor(v1, m, 64);
        v2 += __shfl_xor(v2, m, 64);
    }
    if (ch == 0) { f[row] = v1; g[row] = v2; }
    __syncthreads();
    if (threadIdx.x < 64) {
        bf16x8 frag = *(const bf16x8*)&tr[threadIdx.x][0];
        *(bf16x8*)(whF + ((size_t)seg * 64 + threadIdx.x) * 8) = frag;
    }
}

// ---------------------------------------------------------------------------
// K2: global max of g (analytic softmax bound)
// ---------------------------------------------------------------------------
__global__ __launch_bounds__(256) void k2_gmax(const float* __restrict__ g,
                                               float* __restrict__ gmax)
{
    __shared__ float red[256];
    float m = -1e30f;
    for (int i = threadIdx.x; i < NN; i += 256) m = fmaxf(m, g[i]);
    red[threadIdx.x] = m;
    __syncthreads();
    for (int s = 128; s > 0; s >>= 1) {
        if ((int)threadIdx.x < s) red[threadIdx.x] = fmaxf(red[threadIdx.x], red[threadIdx.x + s]);
        __syncthreads();
    }
    if (threadIdx.x == 0) *gmax = red[0];
}

// ---------------------------------------------------------------------------
// K3: masked-softmax-weighted accumulation, LDS-staged (GEMM pattern).
// Block = 4 waves / 64 rows; chunk = 512 cols; sub-tile = 64 cols (8 KB whF
// slice) double-buffered in LDS. Next sub-tile's whF/mask/g prefetched into
// registers during compute (T14 split), ds_write after post-compute barrier.
// Row-sum via 5th MFMA against an all-ones B-fragment.
// ---------------------------------------------------------------------------
__global__ __launch_bounds__(256, 4) void k3_attn(const unsigned int* __restrict__ msk,
                                                  const unsigned short* __restrict__ whF,
                                                  const float* __restrict__ f,
                                                  const float* __restrict__ g,
                                                  const float* __restrict__ gmaxp,
                                                  float* __restrict__ accP,
                                                  float* __restrict__ lP)
{
    const int tid  = threadIdx.x;
    const int lane = tid & 63;
    const int wave = tid >> 6;
    const int lr16 = lane & 15;
    const int kg   = lane >> 4;
    const int rowBase = blockIdx.x * 64 + wave * 16;
    const int r = rowBase + lr16;
    const int chunk = blockIdx.y;
    const int jStart = chunk * 512;

    __shared__ __align__(16) unsigned short lds[2][4096];   // 2 x 8 KB

    const float L2E = 1.4426950408889634f;
    const float fr = f[r];
    const float gmax = *gmaxp;
    float mm = fr + gmax;
    mm = fmaxf(mm, 0.5f * mm);          // LeakyReLU(f_r + gmax) >= all row scores
    const float mL  = mm * L2E;
    const float frE = fr * L2E - mL;
    const float hm  = -0.5f * mL;

    f32x4 acc0 = {0.f, 0.f, 0.f, 0.f};
    f32x4 acc1 = {0.f, 0.f, 0.f, 0.f};
    f32x4 acc2 = {0.f, 0.f, 0.f, 0.f};
    f32x4 acc3 = {0.f, 0.f, 0.f, 0.f};
    f32x4 accl = {0.f, 0.f, 0.f, 0.f};
    bf16x8 ones;
#pragma unroll
    for (int t = 0; t < 8; ++t) ones[t] = (short)0x3F80;    // bf16 1.0

    const unsigned int* mrow = msk + (size_t)r * (NN / 32);

    // ---- prologue: stage sub-tile 0 into LDS buf0; prefetch its mask/g ----
    {
        const unsigned short* gs = whF + (size_t)(jStart >> 3) * 512;
        bf16x8 s0 = *(const bf16x8*)(gs + tid * 8);
        bf16x8 s1 = *(const bf16x8*)(gs + (tid + 256) * 8);
        *(bf16x8*)&lds[0][tid * 8] = s0;
        *(bf16x8*)&lds[0][(tid + 256) * 8] = s1;
    }
    uint2 mqC = *(const uint2*)(mrow + (jStart >> 5));
    f32x4 gC[4];
    gC[0] = *(const f32x4*)(g + jStart + kg * 8);
    gC[1] = *(const f32x4*)(g + jStart + kg * 8 + 4);
    gC[2] = *(const f32x4*)(g + jStart + 32 + kg * 8);
    gC[3] = *(const f32x4*)(g + jStart + 32 + kg * 8 + 4);
    __syncthreads();

#pragma unroll 2
    for (int sub = 0; sub < 8; ++sub) {
        const int cur = sub & 1;
        const int j0 = jStart + sub * 64;

        // ---- prefetch next sub-tile (regs only; written to LDS later) ----
        bf16x8 n0, n1;
        uint2 mqN;
        f32x4 gN[4];
        if (sub < 7) {
            const unsigned short* gs = whF + (size_t)((j0 + 64) >> 3) * 512;
            n0 = *(const bf16x8*)(gs + tid * 8);
            n1 = *(const bf16x8*)(gs + (tid + 256) * 8);
            mqN = *(const uint2*)(mrow + ((j0 + 64) >> 5));
            gN[0] = *(const f32x4*)(g + j0 + 64 + kg * 8);
            gN[1] = *(const f32x4*)(g + j0 + 64 + kg * 8 + 4);
            gN[2] = *(const f32x4*)(g + j0 + 96 + kg * 8);
            gN[3] = *(const f32x4*)(g + j0 + 96 + kg * 8 + 4);
        }

        // ---- compute 2 steps of 32 cols from LDS[cur] ----
#pragma unroll
        for (int s2 = 0; s2 < 2; ++s2) {
            const unsigned int mwv = s2 ? mqC.y : mqC.x;
            const unsigned int myb = (mwv >> (kg * 8)) & 0xffu;
            const f32x4 G0 = gC[s2 * 2 + 0];
            const f32x4 G1 = gC[s2 * 2 + 1];

            const int slb = (s2 * 4 + kg) * 64;
            bf16x8 b0 = *(const bf16x8*)&lds[cur][(slb +  0 + lr16) * 8];
            bf16x8 b1 = *(const bf16x8*)&lds[cur][(slb + 16 + lr16) * 8];
            bf16x8 b2 = *(const bf16x8*)&lds[cur][(slb + 32 + lr16) * 8];
            bf16x8 b3 = *(const bf16x8*)&lds[cur][(slb + 48 + lr16) * 8];

            bf16x8 af;
#pragma unroll
            for (int t = 0; t < 8; ++t) {
                float gj = (t < 4) ? G0[t] : G1[t - 4];
                float se = __builtin_fmaf(gj, L2E, frE);          // s*L2E - mL
                float u  = __builtin_fmaf(0.5f, se, hm);          // 0.5*s*L2E - mL
                float w  = __builtin_amdgcn_exp2f(fmaxf(se, u));  // <= 1
                w = (myb & (1u << t)) ? w : 0.f;
                af[t] = (short)f2bf(w);
            }
            acc0 = __builtin_amdgcn_mfma_f32_16x16x32_bf16(af, b0, acc0, 0, 0, 0);
            acc1 = __builtin_amdgcn_mfma_f32_16x16x32_bf16(af, b1, acc1, 0, 0, 0);
            acc2 = __builtin_amdgcn_mfma_f32_16x16x32_bf16(af, b2, acc2, 0, 0, 0);
            acc3 = __builtin_amdgcn_mfma_f32_16x16x32_bf16(af, b3, acc3, 0, 0, 0);
            accl = __builtin_amdgcn_mfma_f32_16x16x32_bf16(af, ones, accl, 0, 0, 0);
        }

        __syncthreads();                       // all waves done reading lds[cur^1]
        if (sub < 7) {
            *(bf16x8*)&lds[1 - cur][tid * 8] = n0;
            *(bf16x8*)&lds[1 - cur][(tid + 256) * 8] = n1;
        }
        __syncthreads();                       // staged data visible

        if (sub < 7) {
            mqC = mqN;
            gC[0] = gN[0]; gC[1] = gN[1]; gC[2] = gN[2]; gC[3] = gN[3];
        }
    }

    // accl D-layout: all cols equal; row-in-tile = kg*4 + q
    if (lr16 == 0) {
#pragma unroll
        for (int q = 0; q < 4; ++q)
            lP[(size_t)chunk * NN + rowBase + kg * 4 + q] = accl[q];
    }

    float* ap = accP + (size_t)chunk * NN * OUTC;
#pragma unroll
    for (int q = 0; q < 4; ++q) {
        const int rm = rowBase + kg * 4 + q;
        ap[(size_t)rm * OUTC +  0 + lr16] = acc0[q];
        ap[(size_t)rm * OUTC + 16 + lr16] = acc1[q];
        ap[(size_t)rm * OUTC + 32 + lr16] = acc2[q];
        ap[(size_t)rm * OUTC + 48 + lr16] = acc3[q];
    }
}

// ---------------------------------------------------------------------------
// K4: combine j-chunk partials, normalize, final LeakyReLU
// ---------------------------------------------------------------------------
__global__ __launch_bounds__(256) void k4_final(const float* __restrict__ accP,
                                                const float* __restrict__ lP,
                                                float* __restrict__ out, int js)
{
    const int gid = blockIdx.x * 256 + threadIdx.x;
    const int row = gid >> 6;
    const int ch  = gid & 63;
    float av = 0.f, lv = 0.f;
    for (int c = 0; c < js; ++c) {
        av += accP[((size_t)c * NN + row) * OUTC + ch];
        lv += lP[(size_t)c * NN + row];
    }
    if (lv == 0.f) lv = 1.f;            // NaN guard (unreachable for this data)
    const float hv = av / lv;
    out[(size_t)row * OUTC + ch] = fmaxf(hv, 0.5f * hv);
}

extern "C" void kernel_launch(void* const* d_in, const int* in_sizes, int n_in,
                              void* d_out, int out_size, void* d_ws, size_t ws_size,
                              hipStream_t stream)
{
    const float* h   = (const float*)d_in[0];
    const int*   adj = (const int*)d_in[1];
    const float* W   = (const float*)d_in[2];
    const float* a   = (const float*)d_in[3];
    float* out = (float*)d_out;

    char* ws = (char*)d_ws;
    unsigned short* whF = (unsigned short*)ws;
    size_t off = (size_t)OUTC * NN * sizeof(unsigned short);   // 1 MB fragment-major Wh
    float* f = (float*)(ws + off); off += (size_t)NN * 4;
    float* g = (float*)(ws + off); off += (size_t)NN * 4;
    float* gmax = (float*)(ws + off); off += 256;
    unsigned long long* msk = (unsigned long long*)(ws + off);
    off += (size_t)NN * NN / 8;                                // 8 MB bitmask

    const int js = 16;                                          // 512-col chunks
    float* accP = (float*)(ws + off); off += (size_t)js * NN * OUTC * 4;
    float* lP   = (float*)(ws + off);

    ka_pack<<<dim3(2048), 256, 0, stream>>>(adj, msk);
    k1_wh<<<dim3(NN / 8), 512, 0, stream>>>(h, W, a, whF, f, g);
    k2_gmax<<<1, 256, 0, stream>>>(g, gmax);
    k3_attn<<<dim3(NN / 64, js), 256, 0, stream>>>((const unsigned int*)msk, whF,
                                                   f, g, gmax, accP, lP);
    k4_final<<<dim3(NN * OUTC / 256), 256, 0, stream>>>(accP, lP, out, js);
}

// Round 13
// 429.550 us; speedup vs baseline: 1.1256x; 1.0011x over previous
//
#include <hip/hip_runtime.h>
#include <hip/hip_bf16.h>

#define NN 8192
#define INC 128
#define OUTC 64

typedef __attribute__((ext_vector_type(8))) short bf16x8;
typedef __attribute__((ext_vector_type(4))) float f32x4;
typedef __attribute__((ext_vector_type(4))) int i32x4;

static __device__ __forceinline__ unsigned short f2bf(float x) {
    unsigned int u = __builtin_bit_cast(unsigned int, x);
    u += 0x7fffu + ((u >> 16) & 1u);   // RNE, finite only
    return (unsigned short)(u >> 16);
}

// ---------------------------------------------------------------------------
// KA: bitpack adj (256 MB int32) -> 8 MB bitmask, natural bit order.
// ---------------------------------------------------------------------------
__global__ __launch_bounds__(256) void ka_pack(const int* __restrict__ adj,
                                               unsigned long long* __restrict__ msk)
{
    const int lane = threadIdx.x & 63;
    const int wid  = (blockIdx.x * 256 + threadIdx.x) >> 6;   // 8192 waves
    const int l16  = lane & 15;
    const int g16  = lane >> 4;
#pragma unroll 4
    for (int i = 0; i < 32; ++i) {
        const size_t base = ((size_t)wid * 32 + i) * 256;
        i32x4 v = *(const i32x4*)(adj + base + 4 * lane);
        unsigned int nib = (v[0] > 0 ? 1u : 0u) | (v[1] > 0 ? 2u : 0u)
                         | (v[2] > 0 ? 4u : 0u) | (v[3] > 0 ? 8u : 0u);
        unsigned long long m = (unsigned long long)nib << (4 * l16);
        m |= __shfl_xor(m, 1, 64);
        m |= __shfl_xor(m, 2, 64);
        m |= __shfl_xor(m, 4, 64);
        m |= __shfl_xor(m, 8, 64);
        if (l16 == 0) msk[base / 64 + g16] = m;
    }
}

// ---------------------------------------------------------------------------
// K1: Wh = h @ W in fragment-major bf16 layout; f = Wh@a1, g = Wh@a2.
// ---------------------------------------------------------------------------
__global__ __launch_bounds__(512) void k1_wh(const float* __restrict__ h,
                                             const float* __restrict__ W,
                                             const float* __restrict__ a,
                                             unsigned short* __restrict__ whF,
                                             float* __restrict__ f,
                                             float* __restrict__ g)
{
    const int wave = threadIdx.x >> 6;
    const int ch   = threadIdx.x & 63;
    const int seg  = blockIdx.x;
    const int row  = seg * 8 + wave;
    const f32x4* h4 = (const f32x4*)(h + (size_t)row * INC);
    float acc = 0.f;
#pragma unroll 8
    for (int k4 = 0; k4 < INC / 4; ++k4) {
        f32x4 hv = h4[k4];
        acc += hv[0] * W[(k4 * 4 + 0) * OUTC + ch];
        acc += hv[1] * W[(k4 * 4 + 1) * OUTC + ch];
        acc += hv[2] * W[(k4 * 4 + 2) * OUTC + ch];
        acc += hv[3] * W[(k4 * 4 + 3) * OUTC + ch];
    }
    __shared__ unsigned short tr[64][8];
    tr[ch][wave] = f2bf(acc);

    float v1 = acc * a[ch];
    float v2 = acc * a[64 + ch];
#pragma unroll
    for (int m = 1; m < 64; m <<= 1) {
        v1 += __shfl_xor(v1, m, 64);
        v2 += __shfl_xor(v2, m, 64);
    }
    if (ch == 0) { f[row] = v1; g[row] = v2; }
    __syncthreads();
    if (threadIdx.x < 64) {
        bf16x8 frag = *(const bf16x8*)&tr[threadIdx.x][0];
        *(bf16x8*)(whF + ((size_t)seg * 64 + threadIdx.x) * 8) = frag;
    }
}

// ---------------------------------------------------------------------------
// K2: global max of g (analytic softmax bound)
// ---------------------------------------------------------------------------
__global__ __launch_bounds__(256) void k2_gmax(const float* __restrict__ g,
                                               float* __restrict__ gmax)
{
    __shared__ float red[256];
    float m = -1e30f;
    for (int i = threadIdx.x; i < NN; i += 256) m = fmaxf(m, g[i]);
    red[threadIdx.x] = m;
    __syncthreads();
    for (int s = 128; s > 0; s >>= 1) {
        if ((int)threadIdx.x < s) red[threadIdx.x] = fmaxf(red[threadIdx.x], red[threadIdx.x + s]);
        __syncthreads();
    }
    if (threadIdx.x == 0) *gmax = red[0];
}

// ---------------------------------------------------------------------------
// K3: masked-softmax-weighted accumulation, LDS-staged.
// SLIMMED (r13): mask+g loaded IN PLACE per sub-tile (cache-resident, TLP-
// hidden) instead of register double-buffered -> ~95 live VGPR, no spills
// under the 128-VGPR cap of __launch_bounds__(256,4). Only whF keeps the
// T14 reg-prefetch (n0/n1). Numerics identical to r12.
// ---------------------------------------------------------------------------
__global__ __launch_bounds__(256, 4) void k3_attn(const unsigned int* __restrict__ msk,
                                                  const unsigned short* __restrict__ whF,
                                                  const float* __restrict__ f,
                                                  const float* __restrict__ g,
                                                  const float* __restrict__ gmaxp,
                                                  float* __restrict__ accP,
                                                  float* __restrict__ lP)
{
    const int tid  = threadIdx.x;
    const int lane = tid & 63;
    const int wave = tid >> 6;
    const int lr16 = lane & 15;
    const int kg   = lane >> 4;
    const int rowBase = blockIdx.x * 64 + wave * 16;
    const int r = rowBase + lr16;
    const int chunk = blockIdx.y;
    const int jStart = chunk * 512;

    __shared__ __align__(16) unsigned short lds[2][4096];   // 2 x 8 KB

    const float L2E = 1.4426950408889634f;
    const float fr = f[r];
    const float gmax = *gmaxp;
    float mm = fr + gmax;
    mm = fmaxf(mm, 0.5f * mm);          // LeakyReLU(f_r + gmax) >= all row scores
    const float mL  = mm * L2E;
    const float frE = fr * L2E - mL;
    const float hm  = -0.5f * mL;

    f32x4 acc0 = {0.f, 0.f, 0.f, 0.f};
    f32x4 acc1 = {0.f, 0.f, 0.f, 0.f};
    f32x4 acc2 = {0.f, 0.f, 0.f, 0.f};
    f32x4 acc3 = {0.f, 0.f, 0.f, 0.f};
    f32x4 accl = {0.f, 0.f, 0.f, 0.f};
    bf16x8 ones;
#pragma unroll
    for (int t = 0; t < 8; ++t) ones[t] = (short)0x3F80;    // bf16 1.0

    const unsigned int* mrow = msk + (size_t)r * (NN / 32);

    // ---- prologue: stage sub-tile 0 into LDS buf0 ----
    {
        const unsigned short* gs = whF + (size_t)(jStart >> 3) * 512;
        bf16x8 s0 = *(const bf16x8*)(gs + tid * 8);
        bf16x8 s1 = *(const bf16x8*)(gs + (tid + 256) * 8);
        *(bf16x8*)&lds[0][tid * 8] = s0;
        *(bf16x8*)&lds[0][(tid + 256) * 8] = s1;
    }
    __syncthreads();

#pragma unroll 2
    for (int sub = 0; sub < 8; ++sub) {
        const int cur = sub & 1;
        const int j0 = jStart + sub * 64;

        // ---- current sub-tile's mask + g (L1/L2-resident, loaded in place) --
        const uint2 mq = *(const uint2*)(mrow + (j0 >> 5));
        const f32x4 gA = *(const f32x4*)(g + j0 + kg * 8);
        const f32x4 gB = *(const f32x4*)(g + j0 + kg * 8 + 4);
        const f32x4 gC = *(const f32x4*)(g + j0 + 32 + kg * 8);
        const f32x4 gD = *(const f32x4*)(g + j0 + 32 + kg * 8 + 4);

        // ---- prefetch next whF sub-tile into regs (T14) ----
        bf16x8 n0, n1;
        if (sub < 7) {
            const unsigned short* gs = whF + (size_t)((j0 + 64) >> 3) * 512;
            n0 = *(const bf16x8*)(gs + tid * 8);
            n1 = *(const bf16x8*)(gs + (tid + 256) * 8);
        }

        // ---- compute 2 steps of 32 cols from LDS[cur] ----
#pragma unroll
        for (int s2 = 0; s2 < 2; ++s2) {
            const unsigned int mwv = s2 ? mq.y : mq.x;
            const unsigned int myb = (mwv >> (kg * 8)) & 0xffu;
            const f32x4 G0 = s2 ? gC : gA;
            const f32x4 G1 = s2 ? gD : gB;

            const int slb = (s2 * 4 + kg) * 64;
            bf16x8 b0 = *(const bf16x8*)&lds[cur][(slb +  0 + lr16) * 8];
            bf16x8 b1 = *(const bf16x8*)&lds[cur][(slb + 16 + lr16) * 8];
            bf16x8 b2 = *(const bf16x8*)&lds[cur][(slb + 32 + lr16) * 8];
            bf16x8 b3 = *(const bf16x8*)&lds[cur][(slb + 48 + lr16) * 8];

            bf16x8 af;
#pragma unroll
            for (int t = 0; t < 8; ++t) {
                float gj = (t < 4) ? G0[t] : G1[t - 4];
                float se = __builtin_fmaf(gj, L2E, frE);          // s*L2E - mL
                float u  = __builtin_fmaf(0.5f, se, hm);          // 0.5*s*L2E - mL
                float w  = __builtin_amdgcn_exp2f(fmaxf(se, u));  // <= 1
                w = (myb & (1u << t)) ? w : 0.f;
                af[t] = (short)f2bf(w);
            }
            acc0 = __builtin_amdgcn_mfma_f32_16x16x32_bf16(af, b0, acc0, 0, 0, 0);
            acc1 = __builtin_amdgcn_mfma_f32_16x16x32_bf16(af, b1, acc1, 0, 0, 0);
            acc2 = __builtin_amdgcn_mfma_f32_16x16x32_bf16(af, b2, acc2, 0, 0, 0);
            acc3 = __builtin_amdgcn_mfma_f32_16x16x32_bf16(af, b3, acc3, 0, 0, 0);
            accl = __builtin_amdgcn_mfma_f32_16x16x32_bf16(af, ones, accl, 0, 0, 0);
        }

        __syncthreads();                       // all waves done reading lds[cur^1]
        if (sub < 7) {
            *(bf16x8*)&lds[1 - cur][tid * 8] = n0;
            *(bf16x8*)&lds[1 - cur][(tid + 256) * 8] = n1;
        }
        __syncthreads();                       // staged data visible
    }

    // accl D-layout: all cols equal; row-in-tile = kg*4 + q
    if (lr16 == 0) {
#pragma unroll
        for (int q = 0; q < 4; ++q)
            lP[(size_t)chunk * NN + rowBase + kg * 4 + q] = accl[q];
    }

    float* ap = accP + (size_t)chunk * NN * OUTC;
#pragma unroll
    for (int q = 0; q < 4; ++q) {
        const int rm = rowBase + kg * 4 + q;
        ap[(size_t)rm * OUTC +  0 + lr16] = acc0[q];
        ap[(size_t)rm * OUTC + 16 + lr16] = acc1[q];
        ap[(size_t)rm * OUTC + 32 + lr16] = acc2[q];
        ap[(size_t)rm * OUTC + 48 + lr16] = acc3[q];
    }
}

// ---------------------------------------------------------------------------
// K4: combine j-chunk partials, normalize, final LeakyReLU
// ---------------------------------------------------------------------------
__global__ __launch_bounds__(256) void k4_final(const float* __restrict__ accP,
                                                const float* __restrict__ lP,
                                                float* __restrict__ out, int js)
{
    const int gid = blockIdx.x * 256 + threadIdx.x;
    const int row = gid >> 6;
    const int ch  = gid & 63;
    float av = 0.f, lv = 0.f;
    for (int c = 0; c < js; ++c) {
        av += accP[((size_t)c * NN + row) * OUTC + ch];
        lv += lP[(size_t)c * NN + row];
    }
    if (lv == 0.f) lv = 1.f;            // NaN guard (unreachable for this data)
    const float hv = av / lv;
    out[(size_t)row * OUTC + ch] = fmaxf(hv, 0.5f * hv);
}

extern "C" void kernel_launch(void* const* d_in, const int* in_sizes, int n_in,
                              void* d_out, int out_size, void* d_ws, size_t ws_size,
                              hipStream_t stream)
{
    const float* h   = (const float*)d_in[0];
    const int*   adj = (const int*)d_in[1];
    const float* W   = (const float*)d_in[2];
    const float* a   = (const float*)d_in[3];
    float* out = (float*)d_out;

    char* ws = (char*)d_ws;
    unsigned short* whF = (unsigned short*)ws;
    size_t off = (size_t)OUTC * NN * sizeof(unsigned short);   // 1 MB fragment-major Wh
    float* f = (float*)(ws + off); off += (size_t)NN * 4;
    float* g = (float*)(ws + off); off += (size_t)NN * 4;
    float* gmax = (float*)(ws + off); off += 256;
    unsigned long long* msk = (unsigned long long*)(ws + off);
    off += (size_t)NN * NN / 8;                                // 8 MB bitmask

    const int js = 16;                                          // 512-col chunks
    float* accP = (float*)(ws + off); off += (size_t)js * NN * OUTC * 4;
    float* lP   = (float*)(ws + off);

    ka_pack<<<dim3(2048), 256, 0, stream>>>(adj, msk);
    k1_wh<<<dim3(NN / 8), 512, 0, stream>>>(h, W, a, whF, f, g);
    k2_gmax<<<1, 256, 0, stream>>>(g, gmax);
    k3_attn<<<dim3(NN / 64, js), 256, 0, stream>>>((const unsigned int*)msk, whF,
                                                   f, g, gmax, accP, lP);
    k4_final<<<dim3(NN * OUTC / 256), 256, 0, stream>>>(accP, lP, out, js);
}